// Round 11
// baseline (94.830 us; speedup 1.0000x reference)
//
#include <hip/hip_runtime.h>
#include <math.h>

#define N_PROP 1000
#define NUM_CLASSES 81
#define NFG 80
#define SCORE_THRESH 0.05f
#define NMS_THRESH 0.5f
#define DET_PER_IMG 100
#define PER_CLASS_CAP 100
#define KEPT_CAP (NFG * PER_CLASS_CAP)   /* 8000, fixed */
#define MBITS 512                        /* bitmask NMS path when M <= MBITS */
#define SURV_CAP 4800
// log(1000/16)
#define BBOX_XFORM_CLIP 4.135166556742356f

// ---------------- Kernel 1: per-class fused softmax+decode+sort+NMS -------
// grid = NFG blocks x 1024 threads (16 waves). Softmax is WAVE-PER-ROW:
// lanes read the 81 logits of one row coalesced (2 loads, ~6 cachelines),
// shuffle-reduce max/denominator, grab row[cls] via __shfl -> p into LDS.
// (R10 post-mortem: one-row-per-THREAD made every wave load touch 64 cache
// lines -> 66us; coalescing is the fix, redundancy across blocks is cheap.)
// Writes ALL PER_CLASS_CAP slots for its class every call.
__global__ __launch_bounds__(1024, 1) void k_nms(
    const float* __restrict__ logits,   // [N_PROP, 81]
    const float* __restrict__ deltas,   // [N_PROP, 324]
    const float* __restrict__ pboxes,   // [N_PROP, 4]
    const int* __restrict__ ih, const int* __restrict__ iw,
    float* __restrict__ keptScore,      // [KEPT_CAP]
    unsigned* __restrict__ keptKey,     // [KEPT_CAP]
    float4* __restrict__ keptBox)       // [KEPT_CAP]
{
    const int c   = blockIdx.x;
    const int cls = c + 1;
    const int tid = threadIdx.x;

    __shared__ union {
        struct { float ss[N_PROP]; int si[N_PROP]; float sb[N_PROP * 4]; } in;
        unsigned long long msk[MBITS * (MBITS / 64)];
    } u;                                 // 32768 B
    __shared__ float os[N_PROP];         // 4000 B
    __shared__ float ob[N_PROP * 4];     // 16000 B
    __shared__ float sm_p[N_PROP];       // 4000 B  (this class's probs)
    __shared__ unsigned long long keepw_s[16];
    __shared__ int cnt;

    if (tid == 0) cnt = 0;

    // ---- wave-per-row softmax: 16 waves x 63 passes over 1000 rows ----
    {
        const int wid  = tid >> 6;       // 0..15
        const int lane = tid & 63;
        for (int pass = 0; pass < 63; ++pass) {
            const int n = pass * 16 + wid;
            if (n < N_PROP) {
                const float* row = logits + (size_t)n * NUM_CLASSES;
                const float x0 = row[lane];
                const float x1 = (lane < NUM_CLASSES - 64) ? row[64 + lane]
                                                           : -INFINITY;
                float m = fmaxf(x0, x1);
                #pragma unroll
                for (int o = 32; o > 0; o >>= 1) m = fmaxf(m, __shfl_xor(m, o));
                const float e0 = expf(x0 - m);
                const float e1 = (lane < NUM_CLASSES - 64) ? expf(x1 - m) : 0.0f;
                float s = e0 + e1;
                #pragma unroll
                for (int o = 32; o > 0; o >>= 1) s += __shfl_xor(s, o);
                const float xc = (cls < 64) ? __shfl(x0, cls)
                                            : __shfl(x1, cls - 64);
                if (lane == 0) sm_p[n] = expf(xc - m) / s;
            }
        }
    }
    __syncthreads();

    const float W = (float)iw[0] - 1.0f;
    const float H = (float)ih[0] - 1.0f;

    // ---- compact + decode (scattered reads only for the ~M hits) ----
    if (tid < N_PROP) {
        const int n = tid;
        const float p = sm_p[n];
        if (p > SCORE_THRESH) {
            const float x1b = pboxes[n * 4 + 0];
            const float y1b = pboxes[n * 4 + 1];
            const float x2b = pboxes[n * 4 + 2];
            const float y2b = pboxes[n * 4 + 3];
            const float w  = x2b - x1b + 1.0f;
            const float h  = y2b - y1b + 1.0f;
            const float cx = x1b + 0.5f * w;
            const float cy = y1b + 0.5f * h;
            const float* d = deltas + (size_t)n * (NUM_CLASSES * 4) + cls * 4;
            const float dx = d[0] / 10.0f;
            const float dy = d[1] / 10.0f;
            const float dw = fminf(d[2] / 5.0f, BBOX_XFORM_CLIP);
            const float dh = fminf(d[3] / 5.0f, BBOX_XFORM_CLIP);
            const float pcx = dx * w + cx;
            const float pcy = dy * h + cy;
            const float pw  = expf(dw) * w;
            const float ph  = expf(dh) * h;
            float X1 = pcx - 0.5f * pw;
            float Y1 = pcy - 0.5f * ph;
            float X2 = pcx + 0.5f * pw - 1.0f;
            float Y2 = pcy + 0.5f * ph - 1.0f;
            X1 = fminf(fmaxf(X1, 0.0f), W);
            Y1 = fminf(fmaxf(Y1, 0.0f), H);
            X2 = fminf(fmaxf(X2, 0.0f), W);
            Y2 = fminf(fmaxf(Y2, 0.0f), H);

            const int pos = atomicAdd(&cnt, 1);
            u.in.ss[pos] = p;
            u.in.si[pos] = n;
            u.in.sb[pos * 4 + 0] = X1;
            u.in.sb[pos * 4 + 1] = Y1;
            u.in.sb[pos * 4 + 2] = X2;
            u.in.sb[pos * 4 + 3] = Y2;
        }
    }
    __syncthreads();
    const int M = cnt;

    // ---- rank sort: (score desc, prop_idx asc) ----
    for (int i = tid; i < M; i += 1024) {
        const float s0 = u.in.ss[i];
        const int   i0 = u.in.si[i];
        int r = 0;
        for (int j = 0; j < M; ++j) {
            const float sj = u.in.ss[j];
            r += (sj > s0) || (sj == s0 && u.in.si[j] < i0);
        }
        os[r] = s0;
        ob[r * 4 + 0] = u.in.sb[i * 4 + 0];
        ob[r * 4 + 1] = u.in.sb[i * 4 + 1];
        ob[r * 4 + 2] = u.in.sb[i * 4 + 2];
        ob[r * 4 + 3] = u.in.sb[i * 4 + 3];
    }
    __syncthreads();

    if (M <= MBITS) {
        // ---- bitmask NMS: parallel mask build, barrier-free wave sweep ----
        const int NW = (M + 63) >> 6;

        for (int idx = tid; idx < M * NW; idx += 1024) {
            const int i = idx / NW;
            const int w = idx - i * NW;
            const float ax1 = ob[i * 4 + 0], ay1 = ob[i * 4 + 1];
            const float ax2 = ob[i * 4 + 2], ay2 = ob[i * 4 + 3];
            const float aarea = (ax2 - ax1 + 1.0f) * (ay2 - ay1 + 1.0f);
            unsigned long long bits = 0;
            const int j0 = w << 6;
            const int jb = (i + 1 > j0) ? (i + 1) : j0;
            const int je = (j0 + 64 < M) ? (j0 + 64) : M;
            for (int j = jb; j < je; ++j) {
                const float bx1 = ob[j * 4 + 0], by1 = ob[j * 4 + 1];
                const float bx2 = ob[j * 4 + 2], by2 = ob[j * 4 + 3];
                const float barea = (bx2 - bx1 + 1.0f) * (by2 - by1 + 1.0f);
                const float ix1 = fmaxf(ax1, bx1), iy1 = fmaxf(ay1, by1);
                const float ix2 = fminf(ax2, bx2), iy2 = fminf(ay2, by2);
                const float iw_ = fmaxf(ix2 - ix1 + 1.0f, 0.0f);
                const float ih_ = fmaxf(iy2 - iy1 + 1.0f, 0.0f);
                const float inter = iw_ * ih_;
                const float iou = inter / (aarea + barea - inter);
                if (iou > NMS_THRESH) bits |= 1ull << (j - j0);
            }
            u.msk[i * NW + w] = bits;
        }
        __syncthreads();

        if (tid < 64) {
            const int l = tid;
            const int base = l << 6;
            int nb = M - base;
            nb = nb < 0 ? 0 : (nb > 64 ? 64 : nb);
            unsigned long long keepw =
                (nb == 64) ? ~0ull : ((nb == 0) ? 0ull : ((1ull << nb) - 1ull));
            for (int i = 0; i < M; ++i) {
                const unsigned long long kb = __shfl(keepw, i >> 6);
                if ((kb >> (i & 63)) & 1ull) {
                    const unsigned long long mrow =
                        (l < NW) ? u.msk[i * NW + l] : 0ull;
                    keepw &= ~mrow;
                }
            }
            if (l < 16) keepw_s[l] = keepw;
        }
        __syncthreads();

        unsigned long long kw[16];
        #pragma unroll
        for (int w = 0; w < 16; ++w) kw[w] = keepw_s[w];
        int S = 0;
        #pragma unroll
        for (int w = 0; w < 16; ++w) S += __popcll(kw[w]);
        if (S > PER_CLASS_CAP) S = PER_CLASS_CAP;

        for (int i = tid; i < M; i += 1024) {
            const int w = i >> 6, b = i & 63;
            if ((kw[w] >> b) & 1ull) {
                int sr = 0;
                for (int ww = 0; ww < w; ++ww) sr += __popcll(kw[ww]);
                sr += __popcll(kw[w] & ((b == 0) ? 0ull : (~0ull >> (64 - b))));
                if (sr < PER_CLASS_CAP) {
                    const int slot = c * PER_CLASS_CAP + sr;
                    keptScore[slot] = os[i];
                    keptKey[slot]   = (unsigned)(c * N_PROP + i);
                    keptBox[slot]   = make_float4(ob[i * 4 + 0], ob[i * 4 + 1],
                                                  ob[i * 4 + 2], ob[i * 4 + 3]);
                }
            }
        }
        for (int s = S + tid; s < PER_CLASS_CAP; s += 1024) {
            const int slot = c * PER_CLASS_CAP + s;
            keptScore[slot] = 0.0f;
            keptKey[slot]   = (unsigned)(c * N_PROP + s);
            keptBox[slot]   = make_float4(0.0f, 0.0f, 0.0f, 0.0f);
        }
    } else {
        // legacy serial path (M > 512; never hit by this data)
        int* ok = (int*)u.msk;
        for (int i = tid; i < M; i += 1024) ok[i] = 1;
        __syncthreads();
        for (int i = 0; i < M; ++i) {
            if (ok[i]) {
                const float ax1 = ob[i * 4 + 0], ay1 = ob[i * 4 + 1];
                const float ax2 = ob[i * 4 + 2], ay2 = ob[i * 4 + 3];
                const float aarea = (ax2 - ax1 + 1.0f) * (ay2 - ay1 + 1.0f);
                for (int j = i + 1 + tid; j < M; j += 1024) {
                    const float bx1 = ob[j * 4 + 0], by1 = ob[j * 4 + 1];
                    const float bx2 = ob[j * 4 + 2], by2 = ob[j * 4 + 3];
                    const float barea = (bx2 - bx1 + 1.0f) * (by2 - by1 + 1.0f);
                    const float ix1 = fmaxf(ax1, bx1), iy1 = fmaxf(ay1, by1);
                    const float ix2 = fminf(ax2, bx2), iy2 = fminf(ay2, by2);
                    const float iw_ = fmaxf(ix2 - ix1 + 1.0f, 0.0f);
                    const float ih_ = fmaxf(iy2 - iy1 + 1.0f, 0.0f);
                    const float inter = iw_ * ih_;
                    const float iou = inter / (aarea + barea - inter);
                    if (iou > NMS_THRESH) ok[j] = 0;
                }
            }
            __syncthreads();
        }
        for (int i = tid; i < M; i += 1024) {
            if (ok[i]) {
                int sr = 0;
                for (int j = 0; j < i; ++j) sr += ok[j];
                if (sr < PER_CLASS_CAP) {
                    const int slot = c * PER_CLASS_CAP + sr;
                    keptScore[slot] = os[i];
                    keptKey[slot]   = (unsigned)(c * N_PROP + i);
                    keptBox[slot]   = make_float4(ob[i * 4 + 0], ob[i * 4 + 1],
                                                  ob[i * 4 + 2], ob[i * 4 + 3]);
                }
            }
        }
        int S = 0;
        for (int j = 0; j < M; ++j) S += ok[j];
        if (S > PER_CLASS_CAP) S = PER_CLASS_CAP;
        for (int s = S + tid; s < PER_CLASS_CAP; s += 1024) {
            const int slot = c * PER_CLASS_CAP + s;
            keptScore[slot] = 0.0f;
            keptKey[slot]   = (unsigned)(c * N_PROP + s);
            keptBox[slot]   = make_float4(0.0f, 0.0f, 0.0f, 0.0f);
        }
    }
}

// bucket over score-bits: monotone; scores in (0.05,1) -> buckets ~460..1023;
// zero/invalid -> bucket 0.
__device__ __forceinline__ int bucket_of_bits(unsigned bits) {
    int b = (int)(bits >> 16) - 15232;
    b = b < 0 ? 0 : b;
    return b > 1023 ? 1023 : b;
}

// ---------------- Kernel 2: top-100 via histogram select (ONE block) ------
__global__ __launch_bounds__(1024) void k_topk(
    const float* __restrict__ keptScore,
    const unsigned* __restrict__ keptKey,
    const float4* __restrict__ keptBox,
    float* __restrict__ out)            // [100] scores | [400] boxes | [100] labels
{
    __shared__ union {
        struct {
            int hist[1024];
            int S[1024];
            unsigned long long spk[SURV_CAP];
            unsigned short sid[SURV_CAP];
        } sel;
        unsigned long long pk[KEPT_CAP];
    } u;
    __shared__ int ns_s;
    __shared__ int bstar_s;
    const int tid = threadIdx.x;

    u.sel.hist[tid] = 0;
    __syncthreads();

    for (int e = tid; e < KEPT_CAP; e += 1024) {
        const int b = bucket_of_bits(__float_as_uint(keptScore[e]));
        atomicAdd(&u.sel.hist[b], 1);
    }
    __syncthreads();

    u.sel.S[tid] = u.sel.hist[tid];
    __syncthreads();
    for (int d = 1; d < 1024; d <<= 1) {
        const int v = (tid + d < 1024) ? u.sel.S[tid + d] : 0;
        __syncthreads();
        u.sel.S[tid] += v;
        __syncthreads();
    }

    if (tid == 0) ns_s = 0;
    if (u.sel.S[tid] >= DET_PER_IMG &&
        (tid == 1023 || u.sel.S[tid + 1] < DET_PER_IMG))
        bstar_s = tid;
    __syncthreads();
    const int Bstar = bstar_s;

    for (int e = tid; e < KEPT_CAP; e += 1024) {
        const unsigned bits = __float_as_uint(keptScore[e]);
        if (bucket_of_bits(bits) >= Bstar) {
            const int pos = atomicAdd(&ns_s, 1);
            if (pos < SURV_CAP) {
                u.sel.spk[pos] = ((unsigned long long)bits << 32)
                               | (unsigned)(~keptKey[e]);
                u.sel.sid[pos] = (unsigned short)e;
            }
        }
    }
    __syncthreads();
    const int ns = ns_s;

    if (ns <= SURV_CAP) {
        for (int i = tid; i < ns; i += 1024) {
            const unsigned long long mykey = u.sel.spk[i];
            int r = 0;
            for (int j = 0; j < ns; ++j) r += (int)(u.sel.spk[j] > mykey);
            if (r < DET_PER_IMG) {
                const int e = u.sel.sid[i];
                const float sc = keptScore[e];
                const bool valid = sc > 0.0f;
                out[r] = sc;
                const float4 b = keptBox[e];
                out[DET_PER_IMG + r * 4 + 0] = b.x;
                out[DET_PER_IMG + r * 4 + 1] = b.y;
                out[DET_PER_IMG + r * 4 + 2] = b.z;
                out[DET_PER_IMG + r * 4 + 3] = b.w;
                const unsigned key = keptKey[e];
                out[DET_PER_IMG * 5 + r] = valid ? (float)(key / N_PROP + 1) : 0.0f;
            }
        }
    } else {
        // tie-storm fallback: full in-block rank (correct, slow; never hit)
        __syncthreads();
        for (int j = tid; j < KEPT_CAP; j += 1024)
            u.pk[j] = ((unsigned long long)__float_as_uint(keptScore[j]) << 32)
                    | (unsigned)(~keptKey[j]);
        __syncthreads();
        for (int e = tid; e < KEPT_CAP; e += 1024) {
            const unsigned long long mykey = u.pk[e];
            int r = 0;
            for (int j = 0; j < KEPT_CAP; ++j) r += (int)(u.pk[j] > mykey);
            if (r < DET_PER_IMG) {
                const float sc = keptScore[e];
                const bool valid = sc > 0.0f;
                out[r] = sc;
                const float4 b = keptBox[e];
                out[DET_PER_IMG + r * 4 + 0] = b.x;
                out[DET_PER_IMG + r * 4 + 1] = b.y;
                out[DET_PER_IMG + r * 4 + 2] = b.z;
                out[DET_PER_IMG + r * 4 + 3] = b.w;
                const unsigned key = keptKey[e];
                out[DET_PER_IMG * 5 + r] = valid ? (float)(key / N_PROP + 1) : 0.0f;
            }
        }
    }
}

extern "C" void kernel_launch(void* const* d_in, const int* in_sizes, int n_in,
                              void* d_out, int out_size, void* d_ws, size_t ws_size,
                              hipStream_t stream) {
    const float* logits = (const float*)d_in[0];
    const float* deltas = (const float*)d_in[1];
    const float* pboxes = (const float*)d_in[2];
    const int*   ih     = (const int*)d_in[3];
    const int*   iw     = (const int*)d_in[4];
    float* out = (float*)d_out;

    char* p = (char*)d_ws;
    float4*   keptBox   = (float4*)p;    p += (size_t)KEPT_CAP * 16;
    float*    keptScore = (float*)p;     p += (size_t)KEPT_CAP * 4;
    unsigned* keptKey   = (unsigned*)p;  p += (size_t)KEPT_CAP * 4;

    k_nms<<<NFG, 1024, 0, stream>>>(logits, deltas, pboxes, ih, iw,
                                    keptScore, keptKey, keptBox);
    k_topk<<<1, 1024, 0, stream>>>(keptScore, keptKey, keptBox, out);
}

// Round 12
// 61.748 us; speedup vs baseline: 1.5358x; 1.5358x over previous
//
#include <hip/hip_runtime.h>
#include <math.h>

#define N_PROP 1000
#define NUM_CLASSES 81
#define NFG 80
#define SCORE_THRESH 0.05f
#define NMS_THRESH 0.5f
#define DET_PER_IMG 100
#define PER_CLASS_CAP 100
#define KEPT_CAP (NFG * PER_CLASS_CAP)   /* 8000, fixed */
#define MBITS 512                        /* bitmask NMS path when M <= MBITS */
#define SURV_CAP 3800
// log(1000/16)
#define BBOX_XFORM_CLIP 4.135166556742356f

// ---------------- Kernel 1: parallel softmax -> dense score grid ----------
// grid = N_PROP blocks, 128 threads (R8-proven: high TLP, short blocks).
// Also zeroes the ticket counter for kernel 2 (no fill node needed; kernel
// boundary guarantees visibility).
__global__ __launch_bounds__(128) void k_decode(
    const float* __restrict__ logits,   // [N_PROP, 81]
    float* __restrict__ candS,          // [NFG][N_PROP]
    int* __restrict__ ticket)
{
    const int n = blockIdx.x;
    const int t = threadIdx.x;
    __shared__ float redm[2];
    __shared__ float reds[2];

    if (n == 0 && t == 0) *ticket = 0;

    float l = (t < NUM_CLASSES) ? logits[n * NUM_CLASSES + t] : -INFINITY;

    float m = l;
    #pragma unroll
    for (int o = 32; o > 0; o >>= 1) m = fmaxf(m, __shfl_xor(m, o));
    const int wave = t >> 6;
    if ((t & 63) == 0) redm[wave] = m;
    __syncthreads();
    m = fmaxf(redm[0], redm[1]);

    float e = (t < NUM_CLASSES) ? expf(l - m) : 0.0f;
    float s = e;
    #pragma unroll
    for (int o = 32; o > 0; o >>= 1) s += __shfl_xor(s, o);
    if ((t & 63) == 0) reds[wave] = s;
    __syncthreads();
    s = reds[0] + reds[1];

    if (t >= 1 && t < NUM_CLASSES) {
        const float prob = e / s;
        candS[(size_t)(t - 1) * N_PROP + n] = (prob > SCORE_THRESH) ? prob : 0.0f;
    }
}

// bucket over score-bits: monotone; scores in (0.05,1) -> buckets 460..1023;
// zero/invalid -> bucket 0.
__device__ __forceinline__ int bucket_of_bits(unsigned bits) {
    int b = (int)(bits >> 16) - 15232;
    b = b < 0 ? 0 : b;
    return b > 1023 ? 1023 : b;
}

// ---------------- Kernel 2: per-class NMS + last-block top-100 ------------
// grid = NFG blocks x 256 threads (R8-proven body). After writing its 100
// fixed slots each block takes a ticket (no spinning); the LAST finisher
// runs the histogram top-k (R8-proven) reading kept* from global.
__global__ __launch_bounds__(256) void k_nms(
    const float* __restrict__ candS,
    const float* __restrict__ deltas,   // [N_PROP, 324]
    const float* __restrict__ pboxes,   // [N_PROP, 4]
    const int* __restrict__ ih, const int* __restrict__ iw,
    int* __restrict__ ticket,
    float* __restrict__ keptScore,      // [KEPT_CAP]
    unsigned* __restrict__ keptKey,     // [KEPT_CAP]
    float4* __restrict__ keptBox,       // [KEPT_CAP]
    float* __restrict__ out)            // [100] scores | [400] boxes | [100] labels
{
    const int c   = blockIdx.x;
    const int cls = c + 1;
    const int tid = threadIdx.x;

    __shared__ union {
        struct {
            union {
                struct { float ss[N_PROP]; int si[N_PROP]; float sb[N_PROP * 4]; } in;
                unsigned long long msk[MBITS * (MBITS / 64)];
            } u;                                    // 32768 B
            float os[N_PROP];                       // 4000 B
            float ob[N_PROP * 4];                   // 16000 B
            unsigned long long keepw[16];           // 128 B
        } p2;                                       // 52896 B
        struct {
            int hist[1024];
            int S[1024];
            unsigned long long spk[SURV_CAP];
            unsigned short sid[SURV_CAP];
        } p3;                                       // 46192 B
    } sm;
    __shared__ int cnt;
    __shared__ int vsh;
    __shared__ int ns_s;
    __shared__ int bstar_s;

    if (tid == 0) cnt = 0;
    __syncthreads();

    const float W = (float)iw[0] - 1.0f;
    const float H = (float)ih[0] - 1.0f;

    // ---- compact + re-decode boxes for hits only (~M per class) ----
    for (int n = tid; n < N_PROP; n += 256) {
        const float p = candS[(size_t)c * N_PROP + n];
        if (p > 0.0f) {
            const float x1b = pboxes[n * 4 + 0];
            const float y1b = pboxes[n * 4 + 1];
            const float x2b = pboxes[n * 4 + 2];
            const float y2b = pboxes[n * 4 + 3];
            const float w  = x2b - x1b + 1.0f;
            const float h  = y2b - y1b + 1.0f;
            const float cx = x1b + 0.5f * w;
            const float cy = y1b + 0.5f * h;
            const float* d = deltas + (size_t)n * (NUM_CLASSES * 4) + cls * 4;
            const float dx = d[0] / 10.0f;
            const float dy = d[1] / 10.0f;
            const float dw = fminf(d[2] / 5.0f, BBOX_XFORM_CLIP);
            const float dh = fminf(d[3] / 5.0f, BBOX_XFORM_CLIP);
            const float pcx = dx * w + cx;
            const float pcy = dy * h + cy;
            const float pw  = expf(dw) * w;
            const float ph  = expf(dh) * h;
            float X1 = pcx - 0.5f * pw;
            float Y1 = pcy - 0.5f * ph;
            float X2 = pcx + 0.5f * pw - 1.0f;
            float Y2 = pcy + 0.5f * ph - 1.0f;
            X1 = fminf(fmaxf(X1, 0.0f), W);
            Y1 = fminf(fmaxf(Y1, 0.0f), H);
            X2 = fminf(fmaxf(X2, 0.0f), W);
            Y2 = fminf(fmaxf(Y2, 0.0f), H);

            const int pos = atomicAdd(&cnt, 1);
            sm.p2.u.in.ss[pos] = p;
            sm.p2.u.in.si[pos] = n;
            sm.p2.u.in.sb[pos * 4 + 0] = X1;
            sm.p2.u.in.sb[pos * 4 + 1] = Y1;
            sm.p2.u.in.sb[pos * 4 + 2] = X2;
            sm.p2.u.in.sb[pos * 4 + 3] = Y2;
        }
    }
    __syncthreads();
    const int M = cnt;

    // ---- rank sort: (score desc, prop_idx asc) ----
    for (int i = tid; i < M; i += 256) {
        const float s0 = sm.p2.u.in.ss[i];
        const int   i0 = sm.p2.u.in.si[i];
        int r = 0;
        for (int j = 0; j < M; ++j) {
            const float sj = sm.p2.u.in.ss[j];
            r += (sj > s0) || (sj == s0 && sm.p2.u.in.si[j] < i0);
        }
        sm.p2.os[r] = s0;
        sm.p2.ob[r * 4 + 0] = sm.p2.u.in.sb[i * 4 + 0];
        sm.p2.ob[r * 4 + 1] = sm.p2.u.in.sb[i * 4 + 1];
        sm.p2.ob[r * 4 + 2] = sm.p2.u.in.sb[i * 4 + 2];
        sm.p2.ob[r * 4 + 3] = sm.p2.u.in.sb[i * 4 + 3];
    }
    __syncthreads();

    if (M <= MBITS) {
        // ---- bitmask NMS: parallel mask build, barrier-free wave sweep ----
        const int NW = (M + 63) >> 6;

        for (int idx = tid; idx < M * NW; idx += 256) {
            const int i = idx / NW;
            const int w = idx - i * NW;
            const float ax1 = sm.p2.ob[i * 4 + 0], ay1 = sm.p2.ob[i * 4 + 1];
            const float ax2 = sm.p2.ob[i * 4 + 2], ay2 = sm.p2.ob[i * 4 + 3];
            const float aarea = (ax2 - ax1 + 1.0f) * (ay2 - ay1 + 1.0f);
            unsigned long long bits = 0;
            const int j0 = w << 6;
            const int jb = (i + 1 > j0) ? (i + 1) : j0;
            const int je = (j0 + 64 < M) ? (j0 + 64) : M;
            for (int j = jb; j < je; ++j) {
                const float bx1 = sm.p2.ob[j * 4 + 0], by1 = sm.p2.ob[j * 4 + 1];
                const float bx2 = sm.p2.ob[j * 4 + 2], by2 = sm.p2.ob[j * 4 + 3];
                const float barea = (bx2 - bx1 + 1.0f) * (by2 - by1 + 1.0f);
                const float ix1 = fmaxf(ax1, bx1), iy1 = fmaxf(ay1, by1);
                const float ix2 = fminf(ax2, bx2), iy2 = fminf(ay2, by2);
                const float iw_ = fmaxf(ix2 - ix1 + 1.0f, 0.0f);
                const float ih_ = fmaxf(iy2 - iy1 + 1.0f, 0.0f);
                const float inter = iw_ * ih_;
                const float iou = inter / (aarea + barea - inter);
                if (iou > NMS_THRESH) bits |= 1ull << (j - j0);
            }
            sm.p2.u.msk[i * NW + w] = bits;
        }
        __syncthreads();

        if (tid < 64) {
            const int l = tid;
            const int base = l << 6;
            int nb = M - base;
            nb = nb < 0 ? 0 : (nb > 64 ? 64 : nb);
            unsigned long long keepw =
                (nb == 64) ? ~0ull : ((nb == 0) ? 0ull : ((1ull << nb) - 1ull));
            for (int i = 0; i < M; ++i) {
                const unsigned long long kb = __shfl(keepw, i >> 6);
                if ((kb >> (i & 63)) & 1ull) {
                    const unsigned long long mrow =
                        (l < NW) ? sm.p2.u.msk[i * NW + l] : 0ull;
                    keepw &= ~mrow;
                }
            }
            if (l < 16) sm.p2.keepw[l] = keepw;
        }
        __syncthreads();

        unsigned long long kw[16];
        #pragma unroll
        for (int w = 0; w < 16; ++w) kw[w] = sm.p2.keepw[w];
        int S = 0;
        #pragma unroll
        for (int w = 0; w < 16; ++w) S += __popcll(kw[w]);
        if (S > PER_CLASS_CAP) S = PER_CLASS_CAP;

        for (int i = tid; i < M; i += 256) {
            const int w = i >> 6, b = i & 63;
            if ((kw[w] >> b) & 1ull) {
                int sr = 0;
                for (int ww = 0; ww < w; ++ww) sr += __popcll(kw[ww]);
                sr += __popcll(kw[w] & ((b == 0) ? 0ull : (~0ull >> (64 - b))));
                if (sr < PER_CLASS_CAP) {
                    const int slot = c * PER_CLASS_CAP + sr;
                    keptScore[slot] = sm.p2.os[i];
                    keptKey[slot]   = (unsigned)(c * N_PROP + i);
                    keptBox[slot]   = make_float4(sm.p2.ob[i * 4 + 0], sm.p2.ob[i * 4 + 1],
                                                  sm.p2.ob[i * 4 + 2], sm.p2.ob[i * 4 + 3]);
                }
            }
        }
        for (int s = S + tid; s < PER_CLASS_CAP; s += 256) {
            const int slot = c * PER_CLASS_CAP + s;
            keptScore[slot] = 0.0f;
            keptKey[slot]   = (unsigned)(c * N_PROP + s);
            keptBox[slot]   = make_float4(0.0f, 0.0f, 0.0f, 0.0f);
        }
    } else {
        // legacy serial path (M > 512; never hit by this data)
        int* ok = (int*)sm.p2.u.msk;
        for (int i = tid; i < M; i += 256) ok[i] = 1;
        __syncthreads();
        for (int i = 0; i < M; ++i) {
            if (ok[i]) {
                const float ax1 = sm.p2.ob[i * 4 + 0], ay1 = sm.p2.ob[i * 4 + 1];
                const float ax2 = sm.p2.ob[i * 4 + 2], ay2 = sm.p2.ob[i * 4 + 3];
                const float aarea = (ax2 - ax1 + 1.0f) * (ay2 - ay1 + 1.0f);
                for (int j = i + 1 + tid; j < M; j += 256) {
                    const float bx1 = sm.p2.ob[j * 4 + 0], by1 = sm.p2.ob[j * 4 + 1];
                    const float bx2 = sm.p2.ob[j * 4 + 2], by2 = sm.p2.ob[j * 4 + 3];
                    const float barea = (bx2 - bx1 + 1.0f) * (by2 - by1 + 1.0f);
                    const float ix1 = fmaxf(ax1, bx1), iy1 = fmaxf(ay1, by1);
                    const float ix2 = fminf(ax2, bx2), iy2 = fminf(ay2, by2);
                    const float iw_ = fmaxf(ix2 - ix1 + 1.0f, 0.0f);
                    const float ih_ = fmaxf(iy2 - iy1 + 1.0f, 0.0f);
                    const float inter = iw_ * ih_;
                    const float iou = inter / (aarea + barea - inter);
                    if (iou > NMS_THRESH) ok[j] = 0;
                }
            }
            __syncthreads();
        }
        for (int i = tid; i < M; i += 256) {
            if (ok[i]) {
                int sr = 0;
                for (int j = 0; j < i; ++j) sr += ok[j];
                if (sr < PER_CLASS_CAP) {
                    const int slot = c * PER_CLASS_CAP + sr;
                    keptScore[slot] = sm.p2.os[i];
                    keptKey[slot]   = (unsigned)(c * N_PROP + i);
                    keptBox[slot]   = make_float4(sm.p2.ob[i * 4 + 0], sm.p2.ob[i * 4 + 1],
                                                  sm.p2.ob[i * 4 + 2], sm.p2.ob[i * 4 + 3]);
                }
            }
        }
        int S = 0;
        for (int j = 0; j < M; ++j) S += ok[j];
        if (S > PER_CLASS_CAP) S = PER_CLASS_CAP;
        for (int s = S + tid; s < PER_CLASS_CAP; s += 256) {
            const int slot = c * PER_CLASS_CAP + s;
            keptScore[slot] = 0.0f;
            keptKey[slot]   = (unsigned)(c * N_PROP + s);
            keptBox[slot]   = make_float4(0.0f, 0.0f, 0.0f, 0.0f);
        }
    }

    // ---- last-block ticket (NO spinning; canonical fence+atomic) ----
    __threadfence();
    __syncthreads();
    if (tid == 0)
        vsh = __hip_atomic_fetch_add(ticket, 1, __ATOMIC_ACQ_REL,
                                     __HIP_MEMORY_SCOPE_AGENT);
    __syncthreads();
    if (vsh != NFG - 1) return;          // 79 blocks exit; last one continues
    __threadfence();
    __syncthreads();                     // LDS reuse barrier (p2 -> p3)

    // ---------------- top-100 via histogram select (256 threads) ----------
    for (int b = tid; b < 1024; b += 256) sm.p3.hist[b] = 0;
    __syncthreads();

    for (int e = tid; e < KEPT_CAP; e += 256) {
        const int b = bucket_of_bits(__float_as_uint(keptScore[e]));
        atomicAdd(&sm.p3.hist[b], 1);
    }
    __syncthreads();

    for (int b = tid; b < 1024; b += 256) sm.p3.S[b] = sm.p3.hist[b];
    __syncthreads();
    for (int d = 1; d < 1024; d <<= 1) {
        int v0 = (tid +   0 + d < 1024) ? sm.p3.S[tid +   0 + d] : 0;
        int v1 = (tid + 256 + d < 1024) ? sm.p3.S[tid + 256 + d] : 0;
        int v2 = (tid + 512 + d < 1024) ? sm.p3.S[tid + 512 + d] : 0;
        int v3 = (tid + 768 + d < 1024) ? sm.p3.S[tid + 768 + d] : 0;
        __syncthreads();
        sm.p3.S[tid +   0] += v0;
        sm.p3.S[tid + 256] += v1;
        sm.p3.S[tid + 512] += v2;
        sm.p3.S[tid + 768] += v3;
        __syncthreads();
    }

    if (tid == 0) ns_s = 0;
    for (int b = tid; b < 1024; b += 256) {
        if (sm.p3.S[b] >= DET_PER_IMG &&
            (b == 1023 || sm.p3.S[b + 1] < DET_PER_IMG))
            bstar_s = b;
    }
    __syncthreads();
    const int Bstar = bstar_s;

    for (int e = tid; e < KEPT_CAP; e += 256) {
        const unsigned bits = __float_as_uint(keptScore[e]);
        if (bucket_of_bits(bits) >= Bstar) {
            const int pos = atomicAdd(&ns_s, 1);
            if (pos < SURV_CAP) {
                sm.p3.spk[pos] = ((unsigned long long)bits << 32)
                               | (unsigned)(~keptKey[e]);
                sm.p3.sid[pos] = (unsigned short)e;
            }
        }
    }
    __syncthreads();
    const int ns = ns_s;

    if (ns <= SURV_CAP) {
        for (int i = tid; i < ns; i += 256) {
            const unsigned long long mykey = sm.p3.spk[i];
            int r = 0;
            for (int j = 0; j < ns; ++j) r += (int)(sm.p3.spk[j] > mykey);
            if (r < DET_PER_IMG) {
                const int e = sm.p3.sid[i];
                const float sc = keptScore[e];
                const bool valid = sc > 0.0f;
                out[r] = sc;
                const float4 b = keptBox[e];
                out[DET_PER_IMG + r * 4 + 0] = b.x;
                out[DET_PER_IMG + r * 4 + 1] = b.y;
                out[DET_PER_IMG + r * 4 + 2] = b.z;
                out[DET_PER_IMG + r * 4 + 3] = b.w;
                const unsigned key = keptKey[e];
                out[DET_PER_IMG * 5 + r] = valid ? (float)(key / N_PROP + 1) : 0.0f;
            }
        }
    } else {
        // tie-storm fallback: rank directly from global (correct; never hit)
        for (int e = tid; e < KEPT_CAP; e += 256) {
            const unsigned long long mykey =
                ((unsigned long long)__float_as_uint(keptScore[e]) << 32)
                | (unsigned)(~keptKey[e]);
            int r = 0;
            for (int j = 0; j < KEPT_CAP; ++j) {
                const unsigned long long kj =
                    ((unsigned long long)__float_as_uint(keptScore[j]) << 32)
                    | (unsigned)(~keptKey[j]);
                r += (int)(kj > mykey);
            }
            if (r < DET_PER_IMG) {
                const float sc = keptScore[e];
                const bool valid = sc > 0.0f;
                out[r] = sc;
                const float4 b = keptBox[e];
                out[DET_PER_IMG + r * 4 + 0] = b.x;
                out[DET_PER_IMG + r * 4 + 1] = b.y;
                out[DET_PER_IMG + r * 4 + 2] = b.z;
                out[DET_PER_IMG + r * 4 + 3] = b.w;
                const unsigned key = keptKey[e];
                out[DET_PER_IMG * 5 + r] = valid ? (float)(key / N_PROP + 1) : 0.0f;
            }
        }
    }
}

extern "C" void kernel_launch(void* const* d_in, const int* in_sizes, int n_in,
                              void* d_out, int out_size, void* d_ws, size_t ws_size,
                              hipStream_t stream) {
    const float* logits = (const float*)d_in[0];
    const float* deltas = (const float*)d_in[1];
    const float* pboxes = (const float*)d_in[2];
    const int*   ih     = (const int*)d_in[3];
    const int*   iw     = (const int*)d_in[4];
    float* out = (float*)d_out;

    int* ticket = (int*)d_ws;                            // zeroed by k_decode
    char* p = (char*)d_ws + 256;
    float4*   keptBox   = (float4*)p;    p += (size_t)KEPT_CAP * 16;
    float*    candS     = (float*)p;     p += (size_t)NFG * N_PROP * 4;
    float*    keptScore = (float*)p;     p += (size_t)KEPT_CAP * 4;
    unsigned* keptKey   = (unsigned*)p;  p += (size_t)KEPT_CAP * 4;

    k_decode<<<N_PROP, 128, 0, stream>>>(logits, candS, ticket);
    k_nms<<<NFG, 256, 0, stream>>>(candS, deltas, pboxes, ih, iw, ticket,
                                   keptScore, keptKey, keptBox, out);
}

// Round 13
// 49.023 us; speedup vs baseline: 1.9344x; 1.2596x over previous
//
#include <hip/hip_runtime.h>
#include <math.h>

#define N_PROP 1000
#define NUM_CLASSES 81
#define NFG 80
#define SCORE_THRESH 0.05f
#define NMS_THRESH 0.5f
#define DET_PER_IMG 100
#define PER_CLASS_CAP 100
#define KEPT_CAP (NFG * PER_CLASS_CAP)   /* 8000, fixed */
#define MBITS 512                        /* bitmask NMS path when M <= MBITS */
#define SURV_CAP 4800
// log(1000/16)
#define BBOX_XFORM_CLIP 4.135166556742356f

// ---------------- Kernel 1: parallel softmax -> dense score grid ----------
// grid = 250 blocks x 256 threads; each WAVE handles one proposal row
// independently (no LDS, no barriers). Lane holds row[lane] and row[64+lane]
// (lane<17); shuffle-reduce max/denominator; coalesced candS writes.
__global__ __launch_bounds__(256) void k_decode(
    const float* __restrict__ logits,   // [N_PROP, 81]
    float* __restrict__ candS)          // [NFG][N_PROP]
{
    const int wid  = threadIdx.x >> 6;          // 0..3
    const int lane = threadIdx.x & 63;
    const int n    = blockIdx.x * 4 + wid;      // 250*4 = 1000 exactly

    const float* row = logits + (size_t)n * NUM_CLASSES;
    const float x0 = row[lane];                                  // classes 0..63
    const float x1 = (lane < NUM_CLASSES - 64) ? row[64 + lane]  // classes 64..80
                                               : -INFINITY;

    float m = fmaxf(x0, x1);
    #pragma unroll
    for (int o = 32; o > 0; o >>= 1) m = fmaxf(m, __shfl_xor(m, o));

    const float e0 = expf(x0 - m);
    const float e1 = (lane < NUM_CLASSES - 64) ? expf(x1 - m) : 0.0f;
    float s = e0 + e1;
    #pragma unroll
    for (int o = 32; o > 0; o >>= 1) s += __shfl_xor(s, o);

    if (lane >= 1) {                      // orig class lane -> fg class lane-1
        const float p = e0 / s;
        candS[(size_t)(lane - 1) * N_PROP + n] = (p > SCORE_THRESH) ? p : 0.0f;
    }
    if (lane < NUM_CLASSES - 64) {        // orig class 64+lane -> fg 63+lane
        const float p = e1 / s;
        candS[(size_t)(63 + lane) * N_PROP + n] = (p > SCORE_THRESH) ? p : 0.0f;
    }
}

// ---------------- Kernel 2: per-class compact+decode+sort + bitmask NMS ---
// grid = NFG blocks, 256 threads (R8-proven). Writes ALL PER_CLASS_CAP slots.
__global__ __launch_bounds__(256) void k_nms(
    const float* __restrict__ candS,
    const float* __restrict__ deltas,   // [N_PROP, 324]
    const float* __restrict__ pboxes,   // [N_PROP, 4]
    const int* __restrict__ ih, const int* __restrict__ iw,
    float* __restrict__ keptScore,      // [KEPT_CAP]
    unsigned* __restrict__ keptKey,     // [KEPT_CAP]
    float4* __restrict__ keptBox)       // [KEPT_CAP]
{
    const int c   = blockIdx.x;
    const int cls = c + 1;
    const int tid = threadIdx.x;

    __shared__ union {
        struct { float ss[N_PROP]; int si[N_PROP]; float sb[N_PROP * 4]; } in;
        unsigned long long msk[MBITS * (MBITS / 64)];
    } u;
    __shared__ float os[N_PROP];
    __shared__ float ob[N_PROP * 4];
    __shared__ unsigned long long keepw_s[16];
    __shared__ int cnt;

    if (tid == 0) cnt = 0;
    __syncthreads();

    const float W = (float)iw[0] - 1.0f;
    const float H = (float)ih[0] - 1.0f;

    for (int n = tid; n < N_PROP; n += 256) {
        const float p = candS[(size_t)c * N_PROP + n];
        if (p > 0.0f) {
            const float x1b = pboxes[n * 4 + 0];
            const float y1b = pboxes[n * 4 + 1];
            const float x2b = pboxes[n * 4 + 2];
            const float y2b = pboxes[n * 4 + 3];
            const float w  = x2b - x1b + 1.0f;
            const float h  = y2b - y1b + 1.0f;
            const float cx = x1b + 0.5f * w;
            const float cy = y1b + 0.5f * h;
            const float* d = deltas + (size_t)n * (NUM_CLASSES * 4) + cls * 4;
            const float dx = d[0] / 10.0f;
            const float dy = d[1] / 10.0f;
            const float dw = fminf(d[2] / 5.0f, BBOX_XFORM_CLIP);
            const float dh = fminf(d[3] / 5.0f, BBOX_XFORM_CLIP);
            const float pcx = dx * w + cx;
            const float pcy = dy * h + cy;
            const float pw  = expf(dw) * w;
            const float ph  = expf(dh) * h;
            float X1 = pcx - 0.5f * pw;
            float Y1 = pcy - 0.5f * ph;
            float X2 = pcx + 0.5f * pw - 1.0f;
            float Y2 = pcy + 0.5f * ph - 1.0f;
            X1 = fminf(fmaxf(X1, 0.0f), W);
            Y1 = fminf(fmaxf(Y1, 0.0f), H);
            X2 = fminf(fmaxf(X2, 0.0f), W);
            Y2 = fminf(fmaxf(Y2, 0.0f), H);

            const int pos = atomicAdd(&cnt, 1);
            u.in.ss[pos] = p;
            u.in.si[pos] = n;
            u.in.sb[pos * 4 + 0] = X1;
            u.in.sb[pos * 4 + 1] = Y1;
            u.in.sb[pos * 4 + 2] = X2;
            u.in.sb[pos * 4 + 3] = Y2;
        }
    }
    __syncthreads();
    const int M = cnt;

    // rank sort: (score desc, prop_idx asc)
    for (int i = tid; i < M; i += 256) {
        const float s0 = u.in.ss[i];
        const int   i0 = u.in.si[i];
        int r = 0;
        for (int j = 0; j < M; ++j) {
            const float sj = u.in.ss[j];
            r += (sj > s0) || (sj == s0 && u.in.si[j] < i0);
        }
        os[r] = s0;
        ob[r * 4 + 0] = u.in.sb[i * 4 + 0];
        ob[r * 4 + 1] = u.in.sb[i * 4 + 1];
        ob[r * 4 + 2] = u.in.sb[i * 4 + 2];
        ob[r * 4 + 3] = u.in.sb[i * 4 + 3];
    }
    __syncthreads();

    if (M <= MBITS) {
        const int NW = (M + 63) >> 6;

        for (int idx = tid; idx < M * NW; idx += 256) {
            const int i = idx / NW;
            const int w = idx - i * NW;
            const float ax1 = ob[i * 4 + 0], ay1 = ob[i * 4 + 1];
            const float ax2 = ob[i * 4 + 2], ay2 = ob[i * 4 + 3];
            const float aarea = (ax2 - ax1 + 1.0f) * (ay2 - ay1 + 1.0f);
            unsigned long long bits = 0;
            const int j0 = w << 6;
            const int jb = (i + 1 > j0) ? (i + 1) : j0;
            const int je = (j0 + 64 < M) ? (j0 + 64) : M;
            for (int j = jb; j < je; ++j) {
                const float bx1 = ob[j * 4 + 0], by1 = ob[j * 4 + 1];
                const float bx2 = ob[j * 4 + 2], by2 = ob[j * 4 + 3];
                const float barea = (bx2 - bx1 + 1.0f) * (by2 - by1 + 1.0f);
                const float ix1 = fmaxf(ax1, bx1), iy1 = fmaxf(ay1, by1);
                const float ix2 = fminf(ax2, bx2), iy2 = fminf(ay2, by2);
                const float iw_ = fmaxf(ix2 - ix1 + 1.0f, 0.0f);
                const float ih_ = fmaxf(iy2 - iy1 + 1.0f, 0.0f);
                const float inter = iw_ * ih_;
                const float iou = inter / (aarea + barea - inter);
                if (iou > NMS_THRESH) bits |= 1ull << (j - j0);
            }
            u.msk[i * NW + w] = bits;
        }
        __syncthreads();

        if (tid < 64) {
            const int l = tid;
            const int base = l << 6;
            int nb = M - base;
            nb = nb < 0 ? 0 : (nb > 64 ? 64 : nb);
            unsigned long long keepw =
                (nb == 64) ? ~0ull : ((nb == 0) ? 0ull : ((1ull << nb) - 1ull));
            for (int i = 0; i < M; ++i) {
                const unsigned long long kb = __shfl(keepw, i >> 6);
                if ((kb >> (i & 63)) & 1ull) {
                    const unsigned long long mrow =
                        (l < NW) ? u.msk[i * NW + l] : 0ull;
                    keepw &= ~mrow;
                }
            }
            if (l < 16) keepw_s[l] = keepw;
        }
        __syncthreads();

        unsigned long long kw[16];
        #pragma unroll
        for (int w = 0; w < 16; ++w) kw[w] = keepw_s[w];
        int S = 0;
        #pragma unroll
        for (int w = 0; w < 16; ++w) S += __popcll(kw[w]);
        if (S > PER_CLASS_CAP) S = PER_CLASS_CAP;

        for (int i = tid; i < M; i += 256) {
            const int w = i >> 6, b = i & 63;
            if ((kw[w] >> b) & 1ull) {
                int sr = 0;
                for (int ww = 0; ww < w; ++ww) sr += __popcll(kw[ww]);
                sr += __popcll(kw[w] & ((b == 0) ? 0ull : (~0ull >> (64 - b))));
                if (sr < PER_CLASS_CAP) {
                    const int slot = c * PER_CLASS_CAP + sr;
                    keptScore[slot] = os[i];
                    keptKey[slot]   = (unsigned)(c * N_PROP + i);
                    keptBox[slot]   = make_float4(ob[i * 4 + 0], ob[i * 4 + 1],
                                                  ob[i * 4 + 2], ob[i * 4 + 3]);
                }
            }
        }
        for (int s = S + tid; s < PER_CLASS_CAP; s += 256) {
            const int slot = c * PER_CLASS_CAP + s;
            keptScore[slot] = 0.0f;
            keptKey[slot]   = (unsigned)(c * N_PROP + s);
            keptBox[slot]   = make_float4(0.0f, 0.0f, 0.0f, 0.0f);
        }
    } else {
        // legacy serial path (M > 512; never hit by this data)
        int* ok = (int*)u.msk;
        for (int i = tid; i < M; i += 256) ok[i] = 1;
        __syncthreads();
        for (int i = 0; i < M; ++i) {
            if (ok[i]) {
                const float ax1 = ob[i * 4 + 0], ay1 = ob[i * 4 + 1];
                const float ax2 = ob[i * 4 + 2], ay2 = ob[i * 4 + 3];
                const float aarea = (ax2 - ax1 + 1.0f) * (ay2 - ay1 + 1.0f);
                for (int j = i + 1 + tid; j < M; j += 256) {
                    const float bx1 = ob[j * 4 + 0], by1 = ob[j * 4 + 1];
                    const float bx2 = ob[j * 4 + 2], by2 = ob[j * 4 + 3];
                    const float barea = (bx2 - bx1 + 1.0f) * (by2 - by1 + 1.0f);
                    const float ix1 = fmaxf(ax1, bx1), iy1 = fmaxf(ay1, by1);
                    const float ix2 = fminf(ax2, bx2), iy2 = fminf(ay2, by2);
                    const float iw_ = fmaxf(ix2 - ix1 + 1.0f, 0.0f);
                    const float ih_ = fmaxf(iy2 - iy1 + 1.0f, 0.0f);
                    const float inter = iw_ * ih_;
                    const float iou = inter / (aarea + barea - inter);
                    if (iou > NMS_THRESH) ok[j] = 0;
                }
            }
            __syncthreads();
        }
        for (int i = tid; i < M; i += 256) {
            if (ok[i]) {
                int sr = 0;
                for (int j = 0; j < i; ++j) sr += ok[j];
                if (sr < PER_CLASS_CAP) {
                    const int slot = c * PER_CLASS_CAP + sr;
                    keptScore[slot] = os[i];
                    keptKey[slot]   = (unsigned)(c * N_PROP + i);
                    keptBox[slot]   = make_float4(ob[i * 4 + 0], ob[i * 4 + 1],
                                                  ob[i * 4 + 2], ob[i * 4 + 3]);
                }
            }
        }
        int S = 0;
        for (int j = 0; j < M; ++j) S += ok[j];
        if (S > PER_CLASS_CAP) S = PER_CLASS_CAP;
        for (int s = S + tid; s < PER_CLASS_CAP; s += 256) {
            const int slot = c * PER_CLASS_CAP + s;
            keptScore[slot] = 0.0f;
            keptKey[slot]   = (unsigned)(c * N_PROP + s);
            keptBox[slot]   = make_float4(0.0f, 0.0f, 0.0f, 0.0f);
        }
    }
}

// bucket over score-bits: monotone; scores in (0.05,1) -> buckets ~460..1023;
// zero/invalid -> bucket 0.
__device__ __forceinline__ int bucket_of_bits(unsigned bits) {
    int b = (int)(bits >> 16) - 15232;
    b = b < 0 ? 0 : b;
    return b > 1023 ? 1023 : b;
}

// ---------------- Kernel 3: top-100 via histogram select (ONE block) ------
__global__ __launch_bounds__(1024) void k_topk(
    const float* __restrict__ keptScore,
    const unsigned* __restrict__ keptKey,
    const float4* __restrict__ keptBox,
    float* __restrict__ out)            // [100] scores | [400] boxes | [100] labels
{
    __shared__ union {
        struct {
            int hist[1024];
            int S[1024];
            unsigned long long spk[SURV_CAP];
            unsigned short sid[SURV_CAP];
        } sel;
        unsigned long long pk[KEPT_CAP];
    } u;
    __shared__ int ns_s;
    __shared__ int bstar_s;
    const int tid = threadIdx.x;

    u.sel.hist[tid] = 0;
    __syncthreads();

    for (int e = tid; e < KEPT_CAP; e += 1024) {
        const int b = bucket_of_bits(__float_as_uint(keptScore[e]));
        atomicAdd(&u.sel.hist[b], 1);
    }
    __syncthreads();

    u.sel.S[tid] = u.sel.hist[tid];
    __syncthreads();
    for (int d = 1; d < 1024; d <<= 1) {
        const int v = (tid + d < 1024) ? u.sel.S[tid + d] : 0;
        __syncthreads();
        u.sel.S[tid] += v;
        __syncthreads();
    }

    if (tid == 0) ns_s = 0;
    if (u.sel.S[tid] >= DET_PER_IMG &&
        (tid == 1023 || u.sel.S[tid + 1] < DET_PER_IMG))
        bstar_s = tid;
    __syncthreads();
    const int Bstar = bstar_s;

    for (int e = tid; e < KEPT_CAP; e += 1024) {
        const unsigned bits = __float_as_uint(keptScore[e]);
        if (bucket_of_bits(bits) >= Bstar) {
            const int pos = atomicAdd(&ns_s, 1);
            if (pos < SURV_CAP) {
                u.sel.spk[pos] = ((unsigned long long)bits << 32)
                               | (unsigned)(~keptKey[e]);
                u.sel.sid[pos] = (unsigned short)e;
            }
        }
    }
    __syncthreads();
    const int ns = ns_s;

    if (ns <= SURV_CAP) {
        for (int i = tid; i < ns; i += 1024) {
            const unsigned long long mykey = u.sel.spk[i];
            int r = 0;
            for (int j = 0; j < ns; ++j) r += (int)(u.sel.spk[j] > mykey);
            if (r < DET_PER_IMG) {
                const int e = u.sel.sid[i];
                const float sc = keptScore[e];
                const bool valid = sc > 0.0f;
                out[r] = sc;
                const float4 b = keptBox[e];
                out[DET_PER_IMG + r * 4 + 0] = b.x;
                out[DET_PER_IMG + r * 4 + 1] = b.y;
                out[DET_PER_IMG + r * 4 + 2] = b.z;
                out[DET_PER_IMG + r * 4 + 3] = b.w;
                const unsigned key = keptKey[e];
                out[DET_PER_IMG * 5 + r] = valid ? (float)(key / N_PROP + 1) : 0.0f;
            }
        }
    } else {
        // tie-storm fallback: full in-block rank (correct, slow; never hit)
        __syncthreads();
        for (int j = tid; j < KEPT_CAP; j += 1024)
            u.pk[j] = ((unsigned long long)__float_as_uint(keptScore[j]) << 32)
                    | (unsigned)(~keptKey[j]);
        __syncthreads();
        for (int e = tid; e < KEPT_CAP; e += 1024) {
            const unsigned long long mykey = u.pk[e];
            int r = 0;
            for (int j = 0; j < KEPT_CAP; ++j) r += (int)(u.pk[j] > mykey);
            if (r < DET_PER_IMG) {
                const float sc = keptScore[e];
                const bool valid = sc > 0.0f;
                out[r] = sc;
                const float4 b = keptBox[e];
                out[DET_PER_IMG + r * 4 + 0] = b.x;
                out[DET_PER_IMG + r * 4 + 1] = b.y;
                out[DET_PER_IMG + r * 4 + 2] = b.z;
                out[DET_PER_IMG + r * 4 + 3] = b.w;
                const unsigned key = keptKey[e];
                out[DET_PER_IMG * 5 + r] = valid ? (float)(key / N_PROP + 1) : 0.0f;
            }
        }
    }
}

extern "C" void kernel_launch(void* const* d_in, const int* in_sizes, int n_in,
                              void* d_out, int out_size, void* d_ws, size_t ws_size,
                              hipStream_t stream) {
    const float* logits = (const float*)d_in[0];
    const float* deltas = (const float*)d_in[1];
    const float* pboxes = (const float*)d_in[2];
    const int*   ih     = (const int*)d_in[3];
    const int*   iw     = (const int*)d_in[4];
    float* out = (float*)d_out;

    char* p = (char*)d_ws;
    float4*   keptBox   = (float4*)p;    p += (size_t)KEPT_CAP * 16;
    float*    candS     = (float*)p;     p += (size_t)NFG * N_PROP * 4;
    float*    keptScore = (float*)p;     p += (size_t)KEPT_CAP * 4;
    unsigned* keptKey   = (unsigned*)p;  p += (size_t)KEPT_CAP * 4;

    k_decode<<<250, 256, 0, stream>>>(logits, candS);
    k_nms<<<NFG, 256, 0, stream>>>(candS, deltas, pboxes, ih, iw,
                                   keptScore, keptKey, keptBox);
    k_topk<<<1, 1024, 0, stream>>>(keptScore, keptKey, keptBox, out);
}